// Round 10
// baseline (189.122 us; speedup 1.0000x reference)
//
#include <hip/hip_runtime.h>
#include <cstdint>
#include <cstddef>

// Problem constants
#define S_LEN 1024
#define BATCH 2
#define DM    1024
#define NH    16
#define DH    64
#define CC    32     // compressed length
#define SB    2048   // S*B rows
#define TSD   128
#define NCHD  8

using short8 = __attribute__((ext_vector_type(8))) short;
using f32x4  = __attribute__((ext_vector_type(4))) float;

__device__ __forceinline__ float b2f(unsigned short u) {
    union { unsigned int i; float f; } v; v.i = ((unsigned int)u) << 16; return v.f;
}
__device__ __forceinline__ unsigned short f2b(float f) {
    union { float f; unsigned int i; } v; v.f = f;
    unsigned int x = v.i;
    unsigned int r = x + 0x7FFFu + ((x >> 16) & 1u);
    return (unsigned short)(r >> 16);
}

__device__ __forceinline__ void async_ld16(const unsigned short* g, unsigned short* l) {
    __builtin_amdgcn_global_load_lds(
        (const __attribute__((address_space(1))) unsigned int*)g,
        (__attribute__((address_space(3))) unsigned int*)l,
        16, 0, 0);
}

// ---------------------------------------------------------------------------
// k_convert: inline dtype sniff. If inputs are bf16, ONLY biases are
// converted (consumers use raw d_in pointers). If fp32, full conversion.
// ---------------------------------------------------------------------------
__global__ __launch_bounds__(256) void k_convert(
    const void* x, const void* qd,
    const void* wq, const void* wk, const void* wv, const void* wo,
    const void* bq, const void* bk, const void* bv, const void* bo,
    int* __restrict__ flag,
    unsigned short* xb, unsigned short* qdb,
    unsigned short* Wqb, unsigned short* Wkb, unsigned short* Wvb, unsigned short* Wob,
    float* biasf)
{
    __shared__ int cnt;
    if (threadIdx.x == 0) cnt = 0;
    __syncthreads();
    {
        const unsigned short* xs = (const unsigned short*)x;
        int local = 0;
        for (int i = threadIdx.x; i < 1024; i += 256) {
            unsigned e = (xs[i * 2] >> 7) & 0xFF;
            if (e >= 90 && e <= 160) local++;
        }
        atomicAdd(&cnt, local);
    }
    __syncthreads();
    const int isbf = (cnt >= 640);
    if (blockIdx.x == 0 && threadIdx.x == 0) *flag = isbf;

    const size_t tid = (size_t)blockIdx.x * 256 + threadIdx.x;
    const size_t stride = (size_t)gridDim.x * 256;

    if (!isbf) {
        auto cv = [&](const void* src, unsigned short* dst, size_t n) {
            const float4* s = (const float4*)src;
            for (size_t i = tid; i < n / 4; i += stride) {
                float4 v = s[i];
                ushort4 o;
                o.x = f2b(v.x); o.y = f2b(v.y); o.z = f2b(v.z); o.w = f2b(v.w);
                ((ushort4*)dst)[i] = o;
            }
        };
        cv(x,  xb,  (size_t)SB * DM);
        cv(qd, qdb, (size_t)CC * DM);
        cv(wq, Wqb, (size_t)DM * DM);
        cv(wk, Wkb, (size_t)DM * DM);
        cv(wv, Wvb, (size_t)DM * DM);
        cv(wo, Wob, (size_t)DM * DM);
    }
    for (size_t i = tid; i < 5 * DM; i += stride) {
        int w = (int)(i >> 10), o = (int)(i & 1023);
        float val;
        if (w == 4) val = 0.f;
        else {
            const void* bp = (w == 0) ? bq : ((w == 1) ? bk : ((w == 2) ? bv : bo));
            val = isbf ? b2f(((const unsigned short*)bp)[o]) : ((const float*)bp)[o];
        }
        biasf[i] = val;
    }
}

// ---------------------------------------------------------------------------
// k_prep: blocks 0..127 -> WvT transpose tiles; 128..191 -> combined biases
// ---------------------------------------------------------------------------
__global__ __launch_bounds__(256) void k_prep(const unsigned short* __restrict__ Wv0,
                                              const unsigned short* __restrict__ Wv1,
                                              const unsigned short* __restrict__ Wk0,
                                              const unsigned short* __restrict__ Wk1,
                                              const int* __restrict__ flag,
                                              const float* __restrict__ biasf,
                                              unsigned short* __restrict__ WvT,
                                              float* __restrict__ b2k,
                                              float* __restrict__ b2v)
{
    const int isbf = *flag;
    const unsigned short* Wvb = isbf ? Wv1 : Wv0;
    const unsigned short* Wkb = isbf ? Wk1 : Wk0;
    const int t = threadIdx.x;
    if (blockIdx.x < 128) {
        const int r0 = (blockIdx.x & 7) * 128;
        const int c0 = (blockIdx.x >> 3) * 64;
        __shared__ unsigned short T[128 * 68];
        for (int u = t; u < 128 * 8; u += 256) {
            int r = u >> 3, cb = (u & 7) * 8;
            *(short8*)&T[r * 68 + cb] = *(const short8*)&Wvb[(size_t)(r0 + r) * DM + c0 + cb];
        }
        __syncthreads();
        for (int u = t; u < 64 * 16; u += 256) {
            int c = u >> 4, r8 = (u & 15) * 8;
            short8 o;
#pragma unroll
            for (int k = 0; k < 8; ++k) o[k] = T[(r8 + k) * 68 + c];
            *(short8*)&WvT[(size_t)(c0 + c) * DM + r0 + r8] = o;
        }
    } else {
        const int idx = blockIdx.x - 128;   // 0..63
        const int set = idx >> 5;
        const int bx = idx & 31;
        const unsigned short* W = set ? Wvb : Wkb;
        const float* bvf = biasf + 2048;
        const float* badd = set ? (biasf + 2048) : (biasf + 1024);
        float* out = set ? b2v : b2k;
        const int w = t >> 6, l = t & 63;
        const int gw = bx * 4 + w;   // 0..127
        for (int i = 0; i < 8; ++i) {
            int row = gw * 8 + i;
            const unsigned short* wr = &W[(size_t)row * DM + l * 16];
            short8 a = *(const short8*)wr;
            short8 b = *(const short8*)(wr + 8);
            float s = 0.f;
#pragma unroll
            for (int j = 0; j < 8; ++j) {
                s += b2f((unsigned short)a[j]) * bvf[l * 16 + j];
                s += b2f((unsigned short)b[j]) * bvf[l * 16 + 8 + j];
            }
#pragma unroll
            for (int m = 1; m < 64; m <<= 1) s += __shfl_xor(s, m);
            if (l == 0) out[row] = s + badd[row];
        }
    }
}

// ---------------------------------------------------------------------------
// GEMM: out[M,N] = (A[M,K] . Bt[N,K]^T + bias[N]) * scale, BK=64.
// A/Bt have converted (0) and raw (1) variants selected by *flag.
// mode: 0 = f32 out, 1 = bf16 out, 2 = flag ? bf16 : f32
// ---------------------------------------------------------------------------
struct GArg {
    const unsigned short* A0;
    const unsigned short* A1;
    const unsigned short* B0;
    const unsigned short* B1;
    const float* bias;
    void* out;
    float scale;
    int mode;
};

__global__ __launch_bounds__(256) void gemm_bt(GArg g0, GArg g1, GArg g2, GArg g3,
                                               const int* __restrict__ flag,
                                               int M, int N, int K)
{
    GArg ga = (blockIdx.z == 0) ? g0 : (blockIdx.z == 1) ? g1 : (blockIdx.z == 2) ? g2 : g3;
    const int isbf = *flag;
    const unsigned short* Ap = isbf ? ga.A1 : ga.A0;
    const unsigned short* Bp = isbf ? ga.B1 : ga.B0;
    const int m0 = blockIdx.y * 128;
    const int n0 = blockIdx.x * 128;
    __shared__ __align__(16) unsigned short As[2][128 * 32];
    __shared__ __align__(16) unsigned short Bs[2][128 * 32];
    const int t = threadIdx.x;
    const int w = t >> 6, l = t & 63;
    const int wy = w >> 1, wx = w & 1;
    const int lr = l >> 2;
    const int lk = (l & 3) * 8;
    const int ln = l & 15;
    const int lq = l >> 4;

    f32x4 acc[4][4] = {};

    const unsigned short* Ab0 = Ap + (size_t)(m0 + w * 32 +      lr) * K + lk;
    const unsigned short* Ab1 = Ap + (size_t)(m0 + w * 32 + 16 + lr) * K + lk;
    const unsigned short* Bb0 = Bp + (size_t)(n0 + w * 32 +      lr) * K + lk;
    const unsigned short* Bb1 = Bp + (size_t)(n0 + w * 32 + 16 + lr) * K + lk;

    for (int kk = 0; kk < K; kk += 64) {
#pragma unroll
        for (int hh = 0; hh < 2; ++hh) {
            async_ld16(Ab0 + kk + hh * 32, &As[hh][w * 1024]);
            async_ld16(Ab1 + kk + hh * 32, &As[hh][w * 1024 + 512]);
            async_ld16(Bb0 + kk + hh * 32, &Bs[hh][w * 1024]);
            async_ld16(Bb1 + kk + hh * 32, &Bs[hh][w * 1024 + 512]);
        }
        __syncthreads();
#pragma unroll
        for (int hh = 0; hh < 2; ++hh) {
            short8 af[4], bfr[4];
#pragma unroll
            for (int i = 0; i < 4; ++i)
                af[i] = *(const short8*)&As[hh][(wy * 64 + i * 16 + ln) * 32 + lq * 8];
#pragma unroll
            for (int j = 0; j < 4; ++j)
                bfr[j] = *(const short8*)&Bs[hh][(wx * 64 + j * 16 + ln) * 32 + lq * 8];
#pragma unroll
            for (int i = 0; i < 4; ++i)
#pragma unroll
                for (int j = 0; j < 4; ++j)
                    acc[i][j] = __builtin_amdgcn_mfma_f32_16x16x32_bf16(af[i], bfr[j], acc[i][j], 0, 0, 0);
        }
        __syncthreads();
    }

    const int f32o = (ga.mode == 0) ? 1 : (ga.mode == 1) ? 0 : (!isbf);
    const float sc = ga.scale;
#pragma unroll
    for (int j = 0; j < 4; ++j) {
        int col = n0 + wx * 64 + j * 16 + ln;
        float bv = ga.bias[col];
#pragma unroll
        for (int i = 0; i < 4; ++i) {
            int row0 = m0 + wy * 64 + i * 16 + lq * 4;
#pragma unroll
            for (int r = 0; r < 4; ++r) {
                float v = (acc[i][j][r] + bv) * sc;
                size_t idx = (size_t)(row0 + r) * N + col;
                if (f32o) ((float*)ga.out)[idx] = v;
                else      ((unsigned short*)ga.out)[idx] = f2b(v);
            }
        }
    }
}

// ---------------------------------------------------------------------------
// gemm_bt_n64: 128x64 tiles, BK=64
// ---------------------------------------------------------------------------
__global__ __launch_bounds__(256) void gemm_bt_n64(GArg g0, GArg g1,
                                                   const int* __restrict__ flag,
                                                   int M, int N, int K)
{
    GArg ga = (blockIdx.z == 0) ? g0 : g1;
    const int isbf = *flag;
    const unsigned short* Ap = isbf ? ga.A1 : ga.A0;
    const unsigned short* Bp = isbf ? ga.B1 : ga.B0;
    const int m0 = blockIdx.y * 128;
    const int n0 = blockIdx.x * 64;
    __shared__ __align__(16) unsigned short As[2][128 * 32];
    __shared__ __align__(16) unsigned short Bs[2][64 * 32];
    const int t = threadIdx.x;
    const int w = t >> 6, l = t & 63;
    const int wy = w >> 1, wx = w & 1;
    const int lr = l >> 2;
    const int lk = (l & 3) * 8;
    const int ln = l & 15;
    const int lq = l >> 4;

    f32x4 acc[4][2] = {};

    const unsigned short* Ab0 = Ap + (size_t)(m0 + w * 32 +      lr) * K + lk;
    const unsigned short* Ab1 = Ap + (size_t)(m0 + w * 32 + 16 + lr) * K + lk;
    const unsigned short* Bb  = Bp + (size_t)(n0 + w * 16 + lr) * K + lk;

    for (int kk = 0; kk < K; kk += 64) {
#pragma unroll
        for (int hh = 0; hh < 2; ++hh) {
            async_ld16(Ab0 + kk + hh * 32, &As[hh][w * 1024]);
            async_ld16(Ab1 + kk + hh * 32, &As[hh][w * 1024 + 512]);
            async_ld16(Bb  + kk + hh * 32, &Bs[hh][w * 512]);
        }
        __syncthreads();
#pragma unroll
        for (int hh = 0; hh < 2; ++hh) {
            short8 af[4], bfr[2];
#pragma unroll
            for (int i = 0; i < 4; ++i)
                af[i] = *(const short8*)&As[hh][(wy * 64 + i * 16 + ln) * 32 + lq * 8];
#pragma unroll
            for (int j = 0; j < 2; ++j)
                bfr[j] = *(const short8*)&Bs[hh][(wx * 32 + j * 16 + ln) * 32 + lq * 8];
#pragma unroll
            for (int i = 0; i < 4; ++i)
#pragma unroll
                for (int j = 0; j < 2; ++j)
                    acc[i][j] = __builtin_amdgcn_mfma_f32_16x16x32_bf16(af[i], bfr[j], acc[i][j], 0, 0, 0);
        }
        __syncthreads();
    }

    const int f32o = (ga.mode == 0) ? 1 : (ga.mode == 1) ? 0 : (!isbf);
    const float sc = ga.scale;
#pragma unroll
    for (int j = 0; j < 2; ++j) {
        int col = n0 + wx * 32 + j * 16 + ln;
        float bv = ga.bias[col];
#pragma unroll
        for (int i = 0; i < 4; ++i) {
            int row0 = m0 + wy * 64 + i * 16 + lq * 4;
#pragma unroll
            for (int r = 0; r < 4; ++r) {
                float v = (acc[i][j][r] + bv) * sc;
                size_t idx = (size_t)(row0 + r) * N + col;
                if (f32o) ((float*)ga.out)[idx] = v;
                else      ((unsigned short*)ga.out)[idx] = f2b(v);
            }
        }
    }
}

// ---------------------------------------------------------------------------
// k_down (MFMA): per (bh, chunk of 128): scores = 0.125 * q_down @ k_d^T via
// 16x16x32 MFMA -> LDS + wbuf; per-chunk max -> cmax; exp-sum vs cmax -> csum
// ---------------------------------------------------------------------------
__global__ __launch_bounds__(256) void k_down(const unsigned short* __restrict__ kd,
                                              const unsigned short* __restrict__ qd0,
                                              const unsigned short* __restrict__ qd1,
                                              const int* __restrict__ flag,
                                              float* __restrict__ wbuf,
                                              float* __restrict__ cmax,
                                              float* __restrict__ csum)
{
    const unsigned short* qdw = (*flag) ? qd1 : qd0;
    const int bh = blockIdx.x;
    const int b = bh >> 4, h = bh & 15;
    const int chunk = blockIdx.y;
    const int s0 = chunk * TSD;
    const int t = threadIdx.x;
    const int w = t >> 6, l = t & 63;
    const int ln = l & 15, lq = l >> 4;

    __shared__ __align__(16) unsigned short QD[32 * 72];   // [c][d]
    __shared__ __align__(16) unsigned short KT[128 * 72];  // [sl][d]
    __shared__ float SS[32 * 132];                         // [c][sl]
    __shared__ float cmf[CC];

    {
        int r = t >> 3, cb = (t & 7) * 8;   // 256 threads exactly cover 32x64
        *(short8*)&QD[r * 72 + cb] = *(const short8*)&qdw[(size_t)r * DM + h * DH + cb];
    }
    for (int u = t; u < 128 * 8; u += 256) {
        int r = u >> 3, cb = (u & 7) * 8;
        *(short8*)&KT[r * 72 + cb] =
            *(const short8*)&kd[(size_t)((s0 + r) * BATCH + b) * DM + h * DH + cb];
    }
    __syncthreads();

    // scores: wave w covers sl = w*32..+32; accG[i][j]: c-tile i, sl-tile j
    f32x4 accG[2][2] = {};
#pragma unroll
    for (int ks = 0; ks < 2; ++ks) {
        short8 a8[2], b8[2];
#pragma unroll
        for (int i = 0; i < 2; ++i)
            a8[i] = *(const short8*)&QD[(i * 16 + ln) * 72 + ks * 32 + lq * 8];
#pragma unroll
        for (int j = 0; j < 2; ++j)
            b8[j] = *(const short8*)&KT[(w * 32 + j * 16 + ln) * 72 + ks * 32 + lq * 8];
#pragma unroll
        for (int i = 0; i < 2; ++i)
#pragma unroll
            for (int j = 0; j < 2; ++j)
                accG[i][j] = __builtin_amdgcn_mfma_f32_16x16x32_bf16(a8[i], b8[j], accG[i][j], 0, 0, 0);
    }
#pragma unroll
    for (int i = 0; i < 2; ++i) {
#pragma unroll
        for (int j = 0; j < 2; ++j) {
            int sl = w * 32 + j * 16 + ln;
#pragma unroll
            for (int r = 0; r < 4; ++r) {
                int c = i * 16 + lq * 4 + r;
                float v = accG[i][j][r] * 0.125f;
                SS[c * 132 + sl] = v;
                wbuf[((size_t)bh * CC + c) * S_LEN + s0 + sl] = v;
            }
        }
    }
    __syncthreads();

    // reductions: thread (c = t>>3, sub = t&7) owns sl = sub*16..+16
    const int c = t >> 3, sub = t & 7;
    float lmax = -3.4e38f;
#pragma unroll
    for (int k = 0; k < 16; ++k) lmax = fmaxf(lmax, SS[c * 132 + sub * 16 + k]);
    lmax = fmaxf(lmax, __shfl_xor(lmax, 1));
    lmax = fmaxf(lmax, __shfl_xor(lmax, 2));
    lmax = fmaxf(lmax, __shfl_xor(lmax, 4));
    if (sub == 0) {
        cmf[c] = lmax;
        cmax[((size_t)bh * CC + c) * NCHD + chunk] = lmax;
    }
    __syncthreads();
    const float cm = cmf[c];
    float es = 0.f;
#pragma unroll
    for (int k = 0; k < 16; ++k) es += __expf(SS[c * 132 + sub * 16 + k] - cm);
    es += __shfl_xor(es, 1);
    es += __shfl_xor(es, 2);
    es += __shfl_xor(es, 4);
    if (sub == 0) csum[((size_t)bh * CC + c) * NCHD + chunk] = es;
}

// ---------------------------------------------------------------------------
// k_wstate: per (bh, seg of 128 cols): w = exp(down-gmax) -> wb (global) and
// Ws (LDS); invn = 1/cumsum; PLUS the two 64-chunk states M[c,d], NT[d,c]
// computed in-block via MFMA (4 sequential stage->transpose->MFMA passes).
// ---------------------------------------------------------------------------
__global__ __launch_bounds__(256) void k_wstate(const float* __restrict__ wbuf,
                                                const float* __restrict__ cmax,
                                                const float* __restrict__ csum,
                                                const unsigned short* __restrict__ vdk,
                                                const unsigned short* __restrict__ vdv,
                                                unsigned short* __restrict__ wb,
                                                float* __restrict__ invn,
                                                float* __restrict__ Mst,
                                                float* __restrict__ NTst)
{
    const int bh = blockIdx.x, seg = blockIdx.y;
    const int b = bh >> 4, h = bh & 15;
    const int t = threadIdx.x;
    const int w = t >> 6, l = t & 63;
    const int ln = l & 15, lq = l >> 4;

    __shared__ float gm[CC];
    __shared__ float basep[CC];
    __shared__ float psum[CC][9];
    __shared__ __align__(16) unsigned short Ws[32 * 136];  // [c][s_local 0..128]
    __shared__ float invt[128 * 36];
    __shared__ __align__(16) unsigned short T[64 * 72];    // [s][d] staging
    __shared__ __align__(16) unsigned short TT[64 * 72];   // [d][s] transposed

    if (t < CC) {
        const size_t cb = (size_t)(bh * CC + t) * NCHD;
        float m = cmax[cb];
#pragma unroll
        for (int g = 1; g < NCHD; ++g) m = fmaxf(m, cmax[cb + g]);
        gm[t] = m;
        float bsum = 0.f;
        for (int k = 0; k < seg; ++k)
            bsum += csum[cb + k] * __expf(cmax[cb + k] - m);
        basep[t] = bsum;
    }
    __syncthreads();

    const int c = t >> 3, sub = t & 7;
    const float gmc = gm[c];
    const size_t rbase = (size_t)bh * 32768 + c * 1024 + seg * 128 + sub * 16;
    float w16[16];
    float s = 0.f;
#pragma unroll
    for (int i = 0; i < 16; ++i) {
        float v = __expf(wbuf[rbase + i] - gmc);
        w16[i] = v; s += v;
    }
    psum[c][sub] = s;
    short8 o0, o1;
#pragma unroll
    for (int i = 0; i < 8; ++i) { o0[i] = f2b(w16[i]); o1[i] = f2b(w16[8 + i]); }
    *(short8*)&wb[rbase] = o0;
    *(short8*)&wb[rbase + 8] = o1;
#pragma unroll
    for (int i = 0; i < 16; ++i) Ws[c * 136 + sub * 16 + i] = f2b(w16[i]);
    __syncthreads();

    float run = basep[c];
    for (int k = 0; k < sub; ++k) run += psum[c][k];
#pragma unroll
    for (int i = 0; i < 16; ++i) {
        run += w16[i];
        invt[(sub * 16 + i) * 36 + c] = 1.0f / fmaxf(run, 1e-30f);
    }
    __syncthreads();

    for (int u = t; u < 128 * 8; u += 256) {
        int r = u >> 3, cb = (u & 7) * 4;
        *(float4*)&invn[(size_t)bh * 32768 + (seg * 128 + r) * 32 + cb] =
            *(const float4*)&invt[r * 36 + cb];
    }

    // state passes: it = (ch2, isv): 0=(0,K) 1=(0,V) 2=(1,K) 3=(1,V)
    for (int it = 0; it < 4; ++it) {
        const int ch2 = it >> 1;
        const int isv = it & 1;
        const int ch = seg * 2 + ch2;
        const int s0 = ch * 64;
        const unsigned short* src = isv ? vdv : vdk;
        for (int u = t; u < 64 * 8; u += 256) {
            int r = u >> 3, cb = (u & 7) * 8;
            *(short8*)&T[r * 72 + cb] =
                *(const short8*)&src[(size_t)((s0 + r) * BATCH + b) * DM + h * DH + cb];
        }
        __syncthreads();   // T staged; also fences prev iter's TT reads
        for (int u = t; u < 64 * 8; u += 256) {
            int d = u >> 3, s8 = (u & 7) * 8;
            short8 o;
#pragma unroll
            for (int k = 0; k < 8; ++k) o[k] = T[(s8 + k) * 72 + d];
            *(short8*)&TT[d * 72 + s8] = o;
        }
        __syncthreads();
        if (!isv) {
            f32x4 accM[2] = {};
#pragma unroll
            for (int ks = 0; ks < 2; ++ks) {
                short8 b8 = *(const short8*)&TT[(w * 16 + ln) * 72 + ks * 32 + lq * 8];
#pragma unroll
                for (int i = 0; i < 2; ++i) {
                    short8 a8 = *(const short8*)&Ws[(i * 16 + ln) * 136 + ch2 * 64 + ks * 32 + lq * 8];
                    accM[i] = __builtin_amdgcn_mfma_f32_16x16x32_bf16(a8, b8, accM[i], 0, 0, 0);
                }
            }
#pragma unroll
            for (int i = 0; i < 2; ++i)
#pragma unroll
                for (int r = 0; r < 4; ++r)
                    Mst[((size_t)(bh * 16 + ch) * 32 + i * 16 + lq * 4 + r) * 64 + w * 16 + ln] = accM[i][r];
        } else {
            f32x4 accN[2] = {};
#pragma unroll
            for (int ks = 0; ks < 2; ++ks) {
                short8 a8 = *(const short8*)&TT[(w * 16 + ln) * 72 + ks * 32 + lq * 8];
#pragma unroll
                for (int j = 0; j < 2; ++j) {
                    short8 b8 = *(const short8*)&Ws[(j * 16 + ln) * 136 + ch2 * 64 + ks * 32 + lq * 8];
                    accN[j] = __builtin_amdgcn_mfma_f32_16x16x32_bf16(a8, b8, accN[j], 0, 0, 0);
                }
            }
#pragma unroll
            for (int j = 0; j < 2; ++j)
#pragma unroll
                for (int r = 0; r < 4; ++r)
                    NTst[((size_t)(bh * 16 + ch) * 64 + w * 16 + lq * 4 + r) * 32 + j * 16 + ln] = accN[j][r];
        }
    }
}

// ---------------------------------------------------------------------------
// k_prefix: exclusive prefix over 16 chunks (f32) -> bf16; y: 0=M, 1=NT
// ---------------------------------------------------------------------------
__global__ __launch_bounds__(256) void k_prefix(const float* __restrict__ Mst,
                                                const float* __restrict__ NTst,
                                                unsigned short* __restrict__ Mcum,
                                                unsigned short* __restrict__ NTcum)
{
    const int bh = blockIdx.x;
    const float* src = blockIdx.y ? NTst : Mst;
    unsigned short* dst = blockIdx.y ? NTcum : Mcum;
    const int e0 = threadIdx.x * 8;
    float run[8];
#pragma unroll
    for (int j = 0; j < 8; ++j) run[j] = 0.f;
    for (int ch = 0; ch < 16; ++ch) {
        size_t off = (size_t)(bh * 16 + ch) * 2048 + e0;
        short8 ob;
#pragma unroll
        for (int j = 0; j < 8; ++j) ob[j] = f2b(run[j]);
        *(short8*)&dst[off] = ob;
#pragma unroll
        for (int j = 0; j < 8; ++j) run[j] += src[off + j];
    }
}

// ---------------------------------------------------------------------------
// k_att (chunked): per (bh, q-tile 64). Uniform work, 7 barriers/block.
// WTd and VTd built by in-LDS transpose (wT buffer eliminated).
// ---------------------------------------------------------------------------
__global__ __launch_bounds__(256) void k_att(
    const unsigned short* __restrict__ qu,
    const unsigned short* __restrict__ vdk,
    const unsigned short* __restrict__ wb,
    const float* __restrict__ invn,
    const unsigned short* __restrict__ vdv,
    const unsigned short* __restrict__ Mcum,
    const unsigned short* __restrict__ NTcum,
    unsigned short* __restrict__ attout)
{
    const int bh = blockIdx.x, b = bh >> 4, h = bh & 15;
    const int qi = blockIdx.y;
    const int s0 = qi * 64;
    const int t = threadIdx.x;
    const int w = t >> 6, l = t & 63;
    const int wy = w >> 1, wx = w & 1;
    const int ln = l & 15, lq = l >> 4;

    __shared__ __align__(16) unsigned short Qs[64 * 72];
    __shared__ __align__(16) unsigned short Gs[64 * 72];
    __shared__ __align__(16) unsigned short Kd[64 * 72];
    __shared__ __align__(16) unsigned short Wd[32 * 72];
    __shared__ __align__(16) unsigned short WTd[64 * 40];
    __shared__ __align__(16) unsigned short VTd[64 * 72];
    __shared__ __align__(16) unsigned short Mc[32 * 72];
    __shared__ __align__(16) unsigned short Nc[64 * 40];

    // P0: stage (vdv rows go into Gs temporarily)
    for (int u = t; u < 64 * 8; u += 256) {
        int r = u >> 3, cb = (u & 7) * 8;
        *(short8*)&Qs[r * 72 + cb] =
            *(const short8*)&qu[(size_t)(s0 + r) * 2048 + b * 1024 + h * 64 + cb];
        *(short8*)&Kd[r * 72 + cb] =
            *(const short8*)&vdk[(size_t)(s0 + r) * 2048 + b * 1024 + h * 64 + cb];
        *(short8*)&Gs[r * 72 + cb] =
            *(const short8*)&vdv[(size_t)(s0 + r) * 2048 + b * 1024 + h * 64 + cb];
    }
    for (int u = t; u < 32 * 8; u += 256) {
        int r = u >> 3, cb = (u & 7) * 8;
        *(short8*)&Wd[r * 72 + cb] =
            *(const short8*)&wb[(size_t)bh * 32768 + r * 1024 + s0 + cb];
        *(short8*)&Mc[r * 72 + cb] =
            *(const short8*)&Mcum[((size_t)(bh * 16 + qi) * 32 + r) * 64 + cb];
    }
    for (int u = t; u < 64 * 4; u += 256) {
        int r = u >> 2, cb = (u & 3) * 8;
        *(short8*)&Nc[r * 40 + cb] =
            *(const short8*)&NTcum[((size_t)(bh * 16 + qi) * 64 + r) * 32 + cb];
    }
    __syncthreads();

    // P1: VTd[d][s] = Gs[s][d]; WTd[s][c] = Wd[c][s]
    for (int u = t; u < 64 * 8; u += 256) {
        int d = u >> 3, s8 = (u & 7) * 8;
        short8 o;
#pragma unroll
        for (int k = 0; k < 8; ++k) o[k] = Gs[(s8 + k) * 72 + d];
        *(short8*)&VTd[d * 72 + s8] = o;
    }
    for (int u = t; u < 64 * 4; u += 256) {
        int s = u >> 2, c8 = (u & 3) * 8;
        short8 o;
#pragma unroll
        for (int k = 0; k < 8; ++k) o[k] = Wd[(c8 + k) * 72 + s];
        *(short8*)&WTd[s * 40 + c8] = o;
    }
    __syncthreads();

    // P2: G = q @ k_diag^T, causal, -> Gs
    {
        f32x4 accG[2][2] = {};
#pragma unroll
        for (int ks = 0; ks < 2; ++ks) {
            short8 a8[2], b8[2];
#pragma unroll
            for (int i = 0; i < 2; ++i)
                a8[i] = *(const short8*)&Qs[(wy * 32 + i * 16 + ln) * 72 + ks * 32 + lq * 8];
#pragma unroll
            for (int j = 0; j < 2; ++j)
                b8[j] = *(const short8*)&Kd[(wx * 32 + j * 16 + ln) * 72 + ks * 32 + lq * 8];
#pragma unroll
            for (int i = 0; i < 2; ++i)
#pragma unroll
                for (int j = 0; j < 2; ++j)
                    accG[i][j] = __builtin_amdgcn_mfma_f32_16x16x32_bf16(a8[i], b8[j], accG[i][j], 0, 0, 0);
        }
        __syncthreads();  // VTd transpose reads of Gs done before overwrite
#pragma unroll
        for (int i = 0; i < 2; ++i) {
            int row = wy * 32 + i * 16 + lq * 4;
#pragma unroll
            for (int j = 0; j < 2; ++j) {
                int col = wx * 32 + j * 16 + ln;
#pragma unroll
                for (int r = 0; r < 4; ++r) {
                    float v = accG[i][j][r];
                    if (col > row + r) v = 0.f;
                    Gs[(row + r) * 72 + col] = f2b(v);
                }
            }
        }
    }
    __syncthreads();

    // P3: up = G @ w_diag^T + q @ Mcum^T
    f32x4 accU[2] = {};
#pragma unroll
    for (int ks = 0; ks < 2; ++ks) {
        short8 ga = *(const short8*)&Gs[(w * 16 + ln) * 72 + ks * 32 + lq * 8];
        short8 qa = *(const short8*)&Qs[(w * 16 + ln) * 72 + ks * 32 + lq * 8];
#pragma unroll
        for (int j = 0; j < 2; ++j) {
            short8 wf = *(const short8*)&Wd[(j * 16 + ln) * 72 + ks * 32 + lq * 8];
            short8 mf = *(const short8*)&Mc[(j * 16 + ln) * 72 + ks * 32 + lq * 8];
            accU[j] = __builtin_amdgcn_mfma_f32_16x16x32_bf16(ga, wf, accU[j], 0, 0, 0);
            accU[j] = __builtin_amdgcn_mfma_f32_16x16x32_bf16(qa, mf, accU[j], 0, 0, 0);
        }
    }
    __syncthreads();

    // P4: softmax(up*invn) -> ptil into Qs (stride 40)
    {
        int rowl = w * 16 + lq * 4;
#pragma unroll
        for (int r = 0; r < 4; ++r) {
            int srow = s0 + rowl + r;
            float inv0 = invn[(size_t)bh * 32768 + srow * 32 + ln];
            float inv1 = invn[(size_t)bh * 32768 + srow * 32 + 16 + ln];
            float l0 = accU[0][r] * inv0;
            float l1 = accU[1][r] * inv1;
            float m = fmaxf(l0, l1);
#pragma unroll
            for (int msk = 1; msk < 16; msk <<= 1) m = fmaxf(m, __shfl_xor(m, msk));
            float e0 = __expf(l0 - m), e1 = __expf(l1 - m);
            float Z = e0 + e1;
#pragma unroll
            for (int msk = 1; msk < 16; msk <<= 1) Z += __shfl_xor(Z, msk);
            float iz = 1.0f / Z;
            Qs[(rowl + r) * 40 + ln]      = f2b(e0 * iz * inv0);
            Qs[(rowl + r) * 40 + 16 + ln] = f2b(e1 * iz * inv1);
        }
    }
    __syncthreads();

    // P5: SC = ptil @ wT_diag^T (K=32), causal, -> Gs
    short8 pa[2];
#pragma unroll
    for (int i = 0; i < 2; ++i)
        pa[i] = *(const short8*)&Qs[(wy * 32 + i * 16 + ln) * 40 + lq * 8];
    {
        f32x4 accS[2][2] = {};
        short8 b8[2];
#pragma unroll
        for (int j = 0; j < 2; ++j)
            b8[j] = *(const short8*)&WTd[(wx * 32 + j * 16 + ln) * 40 + lq * 8];
#pragma unroll
        for (int i = 0; i < 2; ++i)
#pragma unroll
            for (int j = 0; j < 2; ++j)
                accS[i][j] = __builtin_amdgcn_mfma_f32_16x16x32_bf16(pa[i], b8[j], accS[i][j], 0, 0, 0);
#pragma unroll
        for (int i = 0; i < 2; ++i) {
            int row = wy * 32 + i * 16 + lq * 4;
#pragma unroll
            for (int j = 0; j < 2; ++j) {
                int col = wx * 32 + j * 16 + ln;
#pragma unroll
                for (int r = 0; r < 4; ++r) {
                    float v = accS[i][j][r];
                    if (col > row + r) v = 0.f;
                    Gs[(row + r) * 72 + col] = f2b(v);
                }
            }
        }
    }
    __syncthreads();

    // P6: out = SC @ vT_diag^T + ptil @ NTcum^T -> attout
    {
        f32x4 accO[2][2] = {};
        short8 n8[2];
#pragma unroll
        for (int j = 0; j < 2; ++j)
            n8[j] = *(const short8*)&Nc[(wx * 32 + j * 16 + ln) * 40 + lq * 8];
#pragma unroll
        for (int i = 0; i < 2; ++i)
#pragma unroll
            for (int j = 0; j < 2; ++j)
                accO[i][j] = __builtin_amdgcn_mfma_f32_16x16x32_bf16(pa[i], n8[j], accO[i][j], 0, 0, 0);
#pragma unroll
        for (int ks = 0; ks < 2; ++ks) {
            short8 a8[2], b8[2];
#pragma unroll
            for (int i = 0; i < 2; ++i)
                a8[i] = *(const short8*)&Gs[(wy * 32 + i * 16 + ln) * 72 + ks * 32 + lq * 8];
#pragma unroll
            for (int j = 0; j < 2; ++j)
                b8[j] = *(const short8*)&VTd[(wx * 32 + j * 16 + ln) * 72 + ks * 32 + lq * 8];
#pragma unroll
            for (int i = 0; i < 2; ++i)
#pragma unroll
                for (int j = 0; j < 2; ++j)
                    accO[i][j] = __builtin_amdgcn_mfma_f32_16x16x32_bf16(a8[i], b8[j], accO[i][j], 0, 0, 0);
        }
#pragma unroll
        for (int i = 0; i < 2; ++i) {
            int rowb = s0 + wy * 32 + i * 16 + lq * 4;
#pragma unroll
            for (int j = 0; j < 2; ++j) {
                int d = wx * 32 + j * 16 + ln;
#pragma unroll
                for (int r = 0; r < 4; ++r)
                    attout[(size_t)(rowb + r) * 2048 + b * 1024 + h * 64 + d] = f2b(accO[i][j][r]);
            }
        }
    }
}

// ---------------------------------------------------------------------------
extern "C" void kernel_launch(void* const* d_in, const int* in_sizes, int n_in,
                              void* d_out, int out_size, void* d_ws, size_t ws_size,
                              hipStream_t stream)
{
    (void)in_sizes; (void)n_in; (void)out_size; (void)ws_size;
    char* ws = (char*)d_ws;
    const size_t MB = (size_t)1 << 20;
    const size_t KB = (size_t)1 << 10;
    unsigned short* attout = (unsigned short*)(ws + 0 * MB);   // 4 MB
    unsigned short* q_u    = (unsigned short*)(ws + 4 * MB);   // 4 MB (pre-scaled)
    unsigned short* k_d    = (unsigned short*)(ws + 8 * MB);   // 4 MB
    unsigned short* v_dk   = (unsigned short*)(ws + 12 * MB);  // 4 MB
    unsigned short* v_dv   = (unsigned short*)(ws + 16 * MB);  // 4 MB
    float* wbuf = (float*)(ws + 20 * MB);                      // 4 MB (down scores)
    unsigned short* wb  = (unsigned short*)(ws + 24 * MB);     // 2 MB [bh][c][s]
    float* invn = (float*)(ws + 28 * MB);                      // 4 MB [bh][s][c]
    float* Mst  = (float*)(ws + 32 * MB);                      // 4 MB
    float* NTst = (float*)(ws + 36 * MB);                      // 4 MB
    unsigned short* Mcum  = (unsigned short*)(ws + 40 * MB);   // 2 MB
    unsigned short* NTcum = (unsigned short*)(ws + 42 * MB);   // 2 MB
    unsigned short* xb  = (unsigned short*)(ws + 44 * MB);     // 4 MB
    unsigned short* Wqb = (unsigned short*)(ws + 48 * MB);     // 2 MB
    unsigned short* Wkb = (unsigned short*)(ws + 50 * MB);     // 2 MB
    unsigned short* Wvb = (unsigned short*)(ws + 52 * MB);     // 2 MB
    unsigned short* Wob = (unsigned short*)(ws + 54 * MB);     // 2 MB
    unsigned short* WvT = (unsigned short*)(ws + 56 * MB);     // 2 MB
    unsigned short* W2k = (unsigned short*)(ws + 58 * MB);     // 2 MB (Wk·Wv)
    unsigned short* W2v = (unsigned short*)(ws + 60 * MB);     // 2 MB (Wv·Wv)
    unsigned short* qdb = (unsigned short*)(ws + 62 * MB);     // 64 KB
    float* biasf  = (float*)(ws + 62 * MB + 64 * KB);          // 20 KB [bq,bk,bv,bo,zero]
    float* b2k    = (float*)(ws + 62 * MB + 128 * KB);         // 4 KB
    float* b2v    = (float*)(ws + 62 * MB + 132 * KB);         // 4 KB
    float* cmax   = (float*)(ws + 62 * MB + 192 * KB);         // 32 KB
    float* csum   = (float*)(ws + 62 * MB + 256 * KB);         // 32 KB
    int*   flag   = (int*)  (ws + 62 * MB + 320 * KB);

    const unsigned short* xraw  = (const unsigned short*)d_in[0];
    const unsigned short* qdraw = (const unsigned short*)d_in[1];
    const unsigned short* wqraw = (const unsigned short*)d_in[2];
    const unsigned short* wkraw = (const unsigned short*)d_in[4];
    const unsigned short* wvraw = (const unsigned short*)d_in[6];
    const unsigned short* woraw = (const unsigned short*)d_in[8];

    // convert (inline sniff; bf16 case converts only biases)
    k_convert<<<1024, 256, 0, stream>>>(
        d_in[0], d_in[1], d_in[2], d_in[4], d_in[6], d_in[8],
        d_in[3], d_in[5], d_in[7], d_in[9],
        flag, xb, qdb, Wqb, Wkb, Wvb, Wob, biasf);

    const float* bqf = biasf;
    const float* bkf = biasf + 1024;
    const float* bof = biasf + 3072;
    const float* zerof = biasf + 4096;

    // weight prep: WvT + combined biases, then W2k = Wk·Wv, W2v = Wv·Wv
    k_prep<<<192, 256, 0, stream>>>(Wvb, wvraw, Wkb, wkraw, flag, biasf, WvT, b2k, b2v);
    GArg wpk{ Wkb, wkraw, WvT, WvT, zerof, (void*)W2k, 1.0f, 1 };
    GArg wpv{ Wvb, wvraw, WvT, WvT, zerof, (void*)W2v, 1.0f, 1 };
    gemm_bt_n64<<<dim3(16, 8, 2), 256, 0, stream>>>(wpk, wpv, flag, DM, DM, DM);

    // main projections: q_u (scaled), k_d, v_dk, v_dv in ONE launch (512 blocks)
    GArg gq { xb, xraw, Wqb, wqraw, bqf, (void*)q_u, 0.125f, 1 };
    GArg gk { xb, xraw, Wkb, wkraw, bkf, (void*)k_d, 1.0f, 1 };
    GArg gvk{ xb, xraw, W2k, W2k,   b2k, (void*)v_dk, 1.0f, 1 };
    GArg gvv{ xb, xraw, W2v, W2v,   b2v, (void*)v_dv, 1.0f, 1 };
    gemm_bt<<<dim3(8, 16, 4), 256, 0, stream>>>(gq, gk, gvk, gvv, flag, SB, DM, DM);

    // attention mid-section
    k_down<<<dim3(32, NCHD), 256, 0, stream>>>(k_d, qdb, qdraw, flag, wbuf, cmax, csum);
    k_wstate<<<dim3(32, 8), 256, 0, stream>>>(wbuf, cmax, csum, v_dk, v_dv, wb, invn, Mst, NTst);
    k_prefix<<<dim3(32, 2), 256, 0, stream>>>(Mst, NTst, Mcum, NTcum);
    k_att<<<dim3(32, 16), 256, 0, stream>>>(q_u, v_dk, wb, invn, v_dv, Mcum, NTcum, attout);

    // final projection (256 blocks): out dtype follows sniffed input dtype
    GArg go{ attout, attout, Wob, woraw, bof, d_out, 1.0f, 2 };
    gemm_bt_n64<<<dim3(16, 16, 1), 256, 0, stream>>>(go, go, flag, SB, DM, DM);
}